// Round 1
// baseline (5829.634 us; speedup 1.0000x reference)
//
#include <hip/hip_runtime.h>

#define HID 256
#define BATCH 512
#define MENC 16
#define HWIN 25
#define SALSZ 4096
#define BH (BATCH * HID)   // 131072 floats

__device__ __forceinline__ float sigmf(float x) { return 1.0f / (1.0f + __expf(-x)); }

// C[M,N] = A[M,K] @ W[N,K]^T (+ b1[N] + b2[N]) (+ C if accum)
// 64x64 tile, K-step 16, 256 threads, 4x4 microtile.
// LDS tiles stored transposed (k-major) so inner loop uses float4 (b128) reads.
__global__ __launch_bounds__(256)
void gemm_tn(const float* __restrict__ A, const float* __restrict__ W,
             const float* __restrict__ b1, const float* __restrict__ b2,
             float* __restrict__ C,
             int M, int N, int K, int lda, int ldw, int ldc, int accum)
{
    __shared__ float AsT[16][68];  // [k][m_local], row stride 68*4B = 16B-aligned
    __shared__ float WsT[16][68];  // [k][n_local]
    const int t  = threadIdx.x;
    const int tx = t & 15, ty = t >> 4;
    const int m0 = blockIdx.y * 64, n0 = blockIdx.x * 64;
    const int lr = t >> 2;   // 0..63 (tile row)
    const int c4 = t & 3;    // float4 column within 16-wide k tile

    float acc[4][4];
#pragma unroll
    for (int i = 0; i < 4; ++i)
#pragma unroll
        for (int j = 0; j < 4; ++j) acc[i][j] = 0.0f;

    for (int k0 = 0; k0 < K; k0 += 16) {
        float a[4], w[4];
        const int kb = k0 + c4 * 4;
        if (kb + 3 < K) {
            const float4 av = *(const float4*)(A + (size_t)(m0 + lr) * lda + kb);
            a[0] = av.x; a[1] = av.y; a[2] = av.z; a[3] = av.w;
            const float4 wv = *(const float4*)(W + (size_t)(n0 + lr) * ldw + kb);
            w[0] = wv.x; w[1] = wv.y; w[2] = wv.z; w[3] = wv.w;
        } else {
#pragma unroll
            for (int k = 0; k < 4; ++k) {
                a[k] = (kb + k < K) ? A[(size_t)(m0 + lr) * lda + kb + k] : 0.0f;
                w[k] = (kb + k < K) ? W[(size_t)(n0 + lr) * ldw + kb + k] : 0.0f;
            }
        }
        __syncthreads();   // previous iteration's LDS reads complete
#pragma unroll
        for (int k = 0; k < 4; ++k) {
            AsT[c4 * 4 + k][lr] = a[k];
            WsT[c4 * 4 + k][lr] = w[k];
        }
        __syncthreads();
#pragma unroll
        for (int kk = 0; kk < 16; ++kk) {
            const float4 av = *(const float4*)&AsT[kk][ty * 4];
            const float4 wv = *(const float4*)&WsT[kk][tx * 4];
            acc[0][0] += av.x * wv.x; acc[0][1] += av.x * wv.y; acc[0][2] += av.x * wv.z; acc[0][3] += av.x * wv.w;
            acc[1][0] += av.y * wv.x; acc[1][1] += av.y * wv.y; acc[1][2] += av.y * wv.z; acc[1][3] += av.y * wv.w;
            acc[2][0] += av.z * wv.x; acc[2][1] += av.z * wv.y; acc[2][2] += av.z * wv.z; acc[2][3] += av.z * wv.w;
            acc[3][0] += av.w * wv.x; acc[3][1] += av.w * wv.y; acc[3][2] += av.w * wv.z; acc[3][3] += av.w * wv.w;
        }
    }

#pragma unroll
    for (int i = 0; i < 4; ++i) {
        const int m = m0 + ty * 4 + i;
#pragma unroll
        for (int j = 0; j < 4; ++j) {
            const int n = n0 + tx * 4 + j;
            float v = acc[i][j];
            if (b1) v += b1[n];
            if (b2) v += b2[n];
            const size_t idx = (size_t)m * ldc + n;
            if (accum) v += C[idx];
            C[idx] = v;
        }
    }
}

// Fused LSTM step: g[b, gate*256+u] = (xg1? ) + (xg2? ) + h_in @ Whh^T + (bih+bhh?) + (xs@Wxs^T?)
// then c/h update. Block tile: 64 b x 16 u. thread = (bg (4 b's), ul). K fixed = 256.
// W LDS tile rows ordered rl = ul*4 + gate so gates read as one float4.
__global__ __launch_bounds__(256)
void lstm_step(const float* __restrict__ h_in,
               const float* __restrict__ c_in,
               float* __restrict__ c_out,
               float* __restrict__ h_out,
               const float* __restrict__ Whh, int ldw,
               const float* __restrict__ xg1, int s1,
               const float* __restrict__ xg2, int s2,
               const float* __restrict__ bih, const float* __restrict__ bhh,
               const float* __restrict__ xs, const float* __restrict__ Wxs)
{
    __shared__ float HsT[16][68];  // [k][b_local]
    __shared__ float WsT[16][68];  // [k][rl], rl = ul*4 + gate
    const int t  = threadIdx.x;
    const int ul = t & 15;    // local u
    const int bg = t >> 4;    // 0..15, 4 b's each
    const int b0 = blockIdx.x * 64;
    const int u0 = blockIdx.y * 16;
    const int lr = t >> 2;    // 0..63 tile row for loading
    const int c4 = t & 3;

    const int w_ul = lr >> 2, w_g = lr & 3;
    const int wrow = w_g * HID + u0 + w_ul;   // global Whh row for local row lr

    float acc[4][4];  // [gate][i(b)]
#pragma unroll
    for (int g = 0; g < 4; ++g)
#pragma unroll
        for (int i = 0; i < 4; ++i) acc[g][i] = 0.0f;

    for (int k0 = 0; k0 < HID; k0 += 16) {
        const float4 hv = *(const float4*)(h_in + (size_t)(b0 + lr) * HID + k0 + c4 * 4);
        const float4 wv = *(const float4*)(Whh + (size_t)wrow * ldw + k0 + c4 * 4);
        __syncthreads();
        HsT[c4 * 4 + 0][lr] = hv.x; HsT[c4 * 4 + 1][lr] = hv.y;
        HsT[c4 * 4 + 2][lr] = hv.z; HsT[c4 * 4 + 3][lr] = hv.w;
        WsT[c4 * 4 + 0][lr] = wv.x; WsT[c4 * 4 + 1][lr] = wv.y;
        WsT[c4 * 4 + 2][lr] = wv.z; WsT[c4 * 4 + 3][lr] = wv.w;
        __syncthreads();
#pragma unroll
        for (int kk = 0; kk < 16; ++kk) {
            const float4 h4 = *(const float4*)&HsT[kk][bg * 4];
            const float4 w4 = *(const float4*)&WsT[kk][ul * 4];  // x,y,z,w = gates i,f,g,o
            acc[0][0] += w4.x * h4.x; acc[0][1] += w4.x * h4.y; acc[0][2] += w4.x * h4.z; acc[0][3] += w4.x * h4.w;
            acc[1][0] += w4.y * h4.x; acc[1][1] += w4.y * h4.y; acc[1][2] += w4.y * h4.z; acc[1][3] += w4.y * h4.w;
            acc[2][0] += w4.z * h4.x; acc[2][1] += w4.z * h4.y; acc[2][2] += w4.z * h4.z; acc[2][3] += w4.z * h4.w;
            acc[3][0] += w4.w * h4.x; acc[3][1] += w4.w * h4.y; acc[3][2] += w4.w * h4.z; acc[3][3] += w4.w * h4.w;
        }
    }

    const int u = u0 + ul;
#pragma unroll
    for (int i = 0; i < 4; ++i) {
        const int b = b0 + bg * 4 + i;
        float g[4];
#pragma unroll
        for (int gg = 0; gg < 4; ++gg) {
            float v = acc[gg][i];
            const int j = gg * HID + u;
            if (xg1) v += xg1[(size_t)b * s1 + j];
            if (xg2) v += xg2[(size_t)b * s2 + j];
            if (bih) v += bih[j];
            if (bhh) v += bhh[j];
            if (xs)  v += xs[b * 3 + 0] * Wxs[j * 3 + 0]
                        + xs[b * 3 + 1] * Wxs[j * 3 + 1]
                        + xs[b * 3 + 2] * Wxs[j * 3 + 2];
            g[gg] = v;
        }
        const float cprev = c_in[(size_t)b * HID + u];
        const float cnew  = sigmf(g[1]) * cprev + sigmf(g[0]) * tanhf(g[2]);
        const float hnew  = sigmf(g[3]) * tanhf(cnew);
        c_out[(size_t)b * HID + u] = cnew;
        h_out[(size_t)b * HID + u] = hnew;
    }
}

// delta = fuse2 @ out_W^T + out_b ; pred += delta ; out[b, t, :] = pred
__global__ __launch_bounds__(64)
void decoder_tail(const float* __restrict__ fuse2,
                  const float* __restrict__ outW, const float* __restrict__ outb,
                  float* __restrict__ pred, float* __restrict__ out, int tstep)
{
    const int b = blockIdx.x;
    const int t = threadIdx.x;  // 64 = one wave
    float a0 = 0.f, a1 = 0.f, a2 = 0.f;
#pragma unroll
    for (int k = 0; k < 4; ++k) {
        const int u = t + k * 64;
        const float f = fuse2[b * HID + u];
        a0 += f * outW[u];
        a1 += f * outW[HID + u];
        a2 += f * outW[2 * HID + u];
    }
    for (int s = 32; s > 0; s >>= 1) {
        a0 += __shfl_down(a0, s);
        a1 += __shfl_down(a1, s);
        a2 += __shfl_down(a2, s);
    }
    if (t == 0) {
        const float p0 = pred[b * 3 + 0] + a0 + outb[0];
        const float p1 = pred[b * 3 + 1] + a1 + outb[1];
        const float p2 = pred[b * 3 + 2] + a2 + outb[2];
        pred[b * 3 + 0] = p0; pred[b * 3 + 1] = p1; pred[b * 3 + 2] = p2;
        float* o = out + ((size_t)b * HWIN + tstep) * 3;
        o[0] = p0; o[1] = p1; o[2] = p2;
    }
}

extern "C" void kernel_launch(void* const* d_in, const int* in_sizes, int n_in,
                              void* d_out, int out_size, void* d_ws, size_t ws_size,
                              hipStream_t stream)
{
    (void)in_sizes; (void)n_in; (void)out_size; (void)ws_size;
    const float* enc_pos = (const float*)d_in[0];
    const float* enc_sal = (const float*)d_in[1];
    const float* dec_pos = (const float*)d_in[2];
    const float* dec_sal = (const float*)d_in[3];
    const float *pe_Wih = (const float*)d_in[4],  *pe_Whh = (const float*)d_in[5],
                *pe_bih = (const float*)d_in[6],  *pe_bhh = (const float*)d_in[7];
    const float *se_Wih = (const float*)d_in[8],  *se_Whh = (const float*)d_in[9],
                *se_bih = (const float*)d_in[10], *se_bhh = (const float*)d_in[11];
    const float *fe_Wih = (const float*)d_in[12], *fe_Whh = (const float*)d_in[13],
                *fe_bih = (const float*)d_in[14], *fe_bhh = (const float*)d_in[15];
    const float *pd_Wih = (const float*)d_in[16], *pd_Whh = (const float*)d_in[17],
                *pd_bih = (const float*)d_in[18], *pd_bhh = (const float*)d_in[19];
    const float *sd_Wih = (const float*)d_in[20], *sd_Whh = (const float*)d_in[21],
                *sd_bih = (const float*)d_in[22], *sd_bhh = (const float*)d_in[23];
    const float *fd_Wih = (const float*)d_in[24], *fd_Whh = (const float*)d_in[25],
                *fd_bih = (const float*)d_in[26], *fd_bhh = (const float*)d_in[27];
    const float *f2_W = (const float*)d_in[28], *f2_b = (const float*)d_in[29];
    const float *out_W = (const float*)d_in[30], *out_b = (const float*)d_in[31];
    float* out = (float*)d_out;
    float* ws  = (float*)d_ws;

    // workspace layout (floats); total ~33.2M floats ~133 MB
    size_t off = 0;
    float* XG_ENC = ws + off; off += (size_t)8192 * 1024;   // x-projections, reused pe/se/fe
    float* BIG    = ws + off; off += (size_t)12800 * 1024;  // Xg_sd, then Xh2_fd
    float* PE_SEQ = ws + off; off += (size_t)(MENC + 1) * BH;
    float* SE_SEQ = ws + off; off += (size_t)(MENC + 1) * BH;
    float* FE_SEQ = ws + off; off += (size_t)(MENC + 1) * BH;
    float* SD_SEQ = ws + off; off += (size_t)(HWIN + 1) * BH;
    float* PE_C  = ws + off; off += BH;
    float* SE_C  = ws + off; off += BH;
    float* FE_C  = ws + off; off += BH;
    float* FD_C  = ws + off; off += BH;   // scratch c_out for fd (cf must stay intact)
    float* GBIAS = ws + off; off += (size_t)BATCH * 1024;  // hf@fd_Whh^T + fd_bih + fd_bhh
    float* PDH0  = ws + off; off += BH;
    float* PDH1  = ws + off; off += BH;
    float* HFD   = ws + off; off += BH;
    float* FUSE2 = ws + off; off += BH;
    float* PRED  = ws + off; off += (size_t)BATCH * 3;

    // zero initial states (must be re-done every call: deterministic)
    hipMemsetAsync(PE_SEQ, 0, (size_t)BH * 4, stream);
    hipMemsetAsync(SE_SEQ, 0, (size_t)BH * 4, stream);
    hipMemsetAsync(FE_SEQ, 0, (size_t)BH * 4, stream);
    hipMemsetAsync(PE_C, 0, (size_t)BH * 4, stream);
    hipMemsetAsync(SE_C, 0, (size_t)BH * 4, stream);
    hipMemsetAsync(FE_C, 0, (size_t)BH * 4, stream);
    hipMemcpyAsync(PRED, dec_pos, (size_t)BATCH * 3 * 4, hipMemcpyDeviceToDevice, stream);

    auto gemm = [&](const float* A, const float* W, const float* b1, const float* b2,
                    float* C, int M, int N, int K, int lda, int ldw, int ldc, int accum) {
        gemm_tn<<<dim3(N / 64, M / 64), 256, 0, stream>>>(A, W, b1, b2, C, M, N, K, lda, ldw, ldc, accum);
    };
    auto step = [&](const float* h_in, const float* c_in, float* c_out, float* h_out,
                    const float* Whh, int ldw, const float* xg1, int s1,
                    const float* xg2, int s2, const float* bih, const float* bhh,
                    const float* xs, const float* Wxs) {
        lstm_step<<<dim3(BATCH / 64, HID / 16), 256, 0, stream>>>(
            h_in, c_in, c_out, h_out, Whh, ldw, xg1, s1, xg2, s2, bih, bhh, xs, Wxs);
    };

    // ---- encoder: pe LSTM (positions, din=3) ----
    gemm(enc_pos, pe_Wih, nullptr, nullptr, XG_ENC, BATCH * MENC, 1024, 3, 3, 3, 1024, 0);
    for (int t = 0; t < MENC; ++t)
        step(PE_SEQ + (size_t)t * BH, PE_C, PE_C, PE_SEQ + (size_t)(t + 1) * BH,
             pe_Whh, HID, XG_ENC + (size_t)t * 1024, MENC * 1024, nullptr, 0,
             pe_bih, pe_bhh, nullptr, nullptr);

    // ---- encoder: se LSTM (saliency, din=4096) — big GEMM hoisted ----
    gemm(enc_sal, se_Wih, nullptr, nullptr, XG_ENC, BATCH * MENC, 1024, SALSZ, SALSZ, SALSZ, 1024, 0);
    for (int t = 0; t < MENC; ++t)
        step(SE_SEQ + (size_t)t * BH, SE_C, SE_C, SE_SEQ + (size_t)(t + 1) * BH,
             se_Whh, HID, XG_ENC + (size_t)t * 1024, MENC * 1024, nullptr, 0,
             se_bih, se_bhh, nullptr, nullptr);

    // ---- encoder: fe LSTM over conc([out_sal, out_pos]); x-proj as two GEMMs, rows (t,b) ----
    gemm(SE_SEQ + BH, fe_Wih,       nullptr, nullptr, XG_ENC, BATCH * MENC, 1024, HID, HID, 2 * HID, 1024, 0);
    gemm(PE_SEQ + BH, fe_Wih + HID, nullptr, nullptr, XG_ENC, BATCH * MENC, 1024, HID, HID, 2 * HID, 1024, 1);
    for (int t = 0; t < MENC; ++t)
        step(FE_SEQ + (size_t)t * BH, FE_C, FE_C, FE_SEQ + (size_t)(t + 1) * BH,
             fe_Whh, HID, XG_ENC + (size_t)t * BATCH * 1024, 1024, nullptr, 0,
             fe_bih, fe_bhh, nullptr, nullptr);

    // ---- decoder sd chain (independent of pred) ----
    gemm(dec_sal, sd_Wih, nullptr, nullptr, BIG, BATCH * HWIN, 1024, SALSZ, SALSZ, SALSZ, 1024, 0);
    for (int t = 0; t < HWIN; ++t)
        step(t == 0 ? SE_SEQ + (size_t)MENC * BH : SD_SEQ + (size_t)t * BH,
             SE_C, SE_C, SD_SEQ + (size_t)(t + 1) * BH,
             sd_Whh, HID, BIG + (size_t)t * 1024, HWIN * 1024, nullptr, 0,
             sd_bih, sd_bhh, nullptr, nullptr);

    // ---- fd precomputations: h2 half of conc@Wih^T (all t), and fixed-bias from hf ----
    gemm(SD_SEQ + BH, fd_Wih, nullptr, nullptr, BIG, BATCH * HWIN, 1024, HID, HID, 2 * HID, 1024, 0);
    gemm(FE_SEQ + (size_t)MENC * BH, fd_Whh, fd_bih, fd_bhh, GBIAS, BATCH, 1024, HID, HID, HID, 1024, 0);

    // ---- serial decoder loop (pd cell -> fd cell -> f2 -> out) ----
    float* pdh[2] = { PDH0, PDH1 };
    for (int t = 0; t < HWIN; ++t) {
        const float* h1in = (t == 0) ? (PE_SEQ + (size_t)MENC * BH) : pdh[t & 1];
        float* h1out = pdh[(t + 1) & 1];
        // pd: x = pred (B,3) folded in via xs/Wxs
        step(h1in, PE_C, PE_C, h1out, pd_Whh, HID, nullptr, 0, nullptr, 0,
             pd_bih, pd_bhh, PRED, pd_Wih);
        // fd: g = Xh2[t] + h1 @ fd_Wih[:,256:]^T + gbias; c_in = cf (kept intact)
        step(h1out, FE_C, FD_C, HFD, fd_Wih + HID, 2 * HID,
             BIG + (size_t)t * BATCH * 1024, 1024, GBIAS, 1024,
             nullptr, nullptr, nullptr, nullptr);
        // fuse2 = hfd @ f2_W^T + f2_b
        gemm(HFD, f2_W, f2_b, nullptr, FUSE2, BATCH, HID, HID, HID, HID, HID, 0);
        // delta + pred update + output write
        decoder_tail<<<BATCH, 64, 0, stream>>>(FUSE2, out_W, out_b, PRED, out, t);
    }
}

// Round 2
// 3652.151 us; speedup vs baseline: 1.5962x; 1.5962x over previous
//
#include <hip/hip_runtime.h>

#define HID 256
#define BATCH 512
#define MENC 16
#define HWIN 25
#define SALSZ 4096
#define BH (BATCH * HID)   // 131072 floats

typedef __attribute__((ext_vector_type(8))) short bf16x8;
typedef __attribute__((ext_vector_type(4))) float f32x4;

__device__ __forceinline__ float sigmf(float x) { return 1.0f / (1.0f + __expf(-x)); }

__device__ __forceinline__ ushort f2bf(float f) {
    uint32_t u = __float_as_uint(f);
    return (ushort)((u + 0x7fffu + ((u >> 16) & 1u)) >> 16);   // RNE
}

// ---------------- fp32 -> bf16 converters ----------------
__global__ __launch_bounds__(256)
void cvt_f32_bf16(const float* __restrict__ in, ushort* __restrict__ out, int n4)
{
    const int i = blockIdx.x * 256 + threadIdx.x;
    if (i >= n4) return;
    const float4 v = *(const float4*)(in + (size_t)i * 4);
    ushort4 o = make_ushort4(f2bf(v.x), f2bf(v.y), f2bf(v.z), f2bf(v.w));
    *(ushort4*)(out + (size_t)i * 4) = o;
}

// out[(t*512+b)][0:256]=bf16(se_h[t+1][b]), [256:512]=bf16(pe_h[t+1][b]); 8192x512
__global__ __launch_bounds__(256)
void build_conc_bf16(const float* __restrict__ se, const float* __restrict__ pe,
                     ushort* __restrict__ out)
{
    const int i = blockIdx.x * 256 + threadIdx.x;   // each does 4 elems
    const int idx = i * 4;
    const int row = idx >> 9, col = idx & 511;
    const int tt = row >> 9, b = row & 511;
    const float* src = (col < 256) ? se : pe;
    const int c = col & 255;
    const float4 v = *(const float4*)(src + (size_t)(tt + 1) * BH + b * HID + c);
    ushort4 o = make_ushort4(f2bf(v.x), f2bf(v.y), f2bf(v.z), f2bf(v.w));
    *(ushort4*)(out + (size_t)idx) = o;
}

// ---------------- bf16 MFMA GEMM: C[M,N] = A[M,K] @ W[N,K]^T ----------------
// m97 structure: 128x128 tile, BK=32, 4 waves (2x2), 16x16x32 MFMA, 4x4 frags/wave,
// global_load_lds width 16, linear LDS [128][32] bf16 (conflict-free for frag reads).
// Requires: M%128==0, N%128==0, K%32==0, lda/ldw%8==0, 16B-aligned pointers.
#define GLOAD_LDS(gp, lp) \
    __builtin_amdgcn_global_load_lds((const __attribute__((address_space(1))) void*)(gp), \
                                     (__attribute__((address_space(3))) void*)(lp), 16, 0, 0)

__global__ __launch_bounds__(256)
void gemm_mfma_bt(const ushort* __restrict__ A, const ushort* __restrict__ W,
                  float* __restrict__ C, int M, int N, int K,
                  int lda, int ldw, int ldc)
{
    __shared__ ushort As[128 * 32];
    __shared__ ushort Bs[128 * 32];
    const int t    = threadIdx.x;
    const int lane = t & 63, wid = t >> 6;
    const int m0 = blockIdx.y * 128, n0 = blockIdx.x * 128;
    const int wr = wid >> 1, wc = wid & 1;

    f32x4 acc[4][4] = {};

    // staging: issue i covers rows i*64 + wid*16 + lane/4, 16B at col (lane&3)*8
    const int sr = wid * 16 + (lane >> 2);
    const int sk = (lane & 3) * 8;
    const ushort* Ag = A + (size_t)(m0 + sr) * lda + sk;
    const ushort* Wg = W + (size_t)(n0 + sr) * ldw + sk;
    ushort* Al = As + wid * 512;   // wave-uniform LDS base (1KB per wave per issue)
    ushort* Bl = Bs + wid * 512;

    const int fr = lane & 15;          // fragment row/col within 16-subtile
    const int fk = (lane >> 4) * 8;    // fragment k-offset (8 contiguous bf16)

    for (int k0 = 0; k0 < K; k0 += 32) {
        GLOAD_LDS(Ag,                    Al);
        GLOAD_LDS(Ag + (size_t)64 * lda, Al + 2048);
        GLOAD_LDS(Wg,                    Bl);
        GLOAD_LDS(Wg + (size_t)64 * ldw, Bl + 2048);
        Ag += 32; Wg += 32;
        __syncthreads();   // drains vmcnt -> tiles visible

        bf16x8 af[4], bfr[4];
#pragma unroll
        for (int m = 0; m < 4; ++m)
            af[m] = *(const bf16x8*)(As + (wr * 64 + m * 16 + fr) * 32 + fk);
#pragma unroll
        for (int n = 0; n < 4; ++n)
            bfr[n] = *(const bf16x8*)(Bs + (wc * 64 + n * 16 + fr) * 32 + fk);
#pragma unroll
        for (int m = 0; m < 4; ++m)
#pragma unroll
            for (int n = 0; n < 4; ++n)
                acc[m][n] = __builtin_amdgcn_mfma_f32_16x16x32_bf16(af[m], bfr[n], acc[m][n], 0, 0, 0);
        __syncthreads();   // all reads done before next stage overwrites
    }

    const int cl = lane & 15, ch = lane >> 4;
#pragma unroll
    for (int m = 0; m < 4; ++m)
#pragma unroll
        for (int n = 0; n < 4; ++n)
#pragma unroll
            for (int r = 0; r < 4; ++r)
                C[(size_t)(m0 + wr * 64 + m * 16 + ch * 4 + r) * ldc
                  + n0 + wc * 64 + n * 16 + cl] = acc[m][n][r];
}

// ---------------- fp32 tiled GEMM (small/odd-K cases) ----------------
__global__ __launch_bounds__(256)
void gemm_tn(const float* __restrict__ A, const float* __restrict__ W,
             const float* __restrict__ b1, const float* __restrict__ b2,
             float* __restrict__ C,
             int M, int N, int K, int lda, int ldw, int ldc, int accum)
{
    __shared__ float AsT[16][68];
    __shared__ float WsT[16][68];
    const int t  = threadIdx.x;
    const int tx = t & 15, ty = t >> 4;
    const int m0 = blockIdx.y * 64, n0 = blockIdx.x * 64;
    const int lr = t >> 2;
    const int c4 = t & 3;

    float acc[4][4];
#pragma unroll
    for (int i = 0; i < 4; ++i)
#pragma unroll
        for (int j = 0; j < 4; ++j) acc[i][j] = 0.0f;

    for (int k0 = 0; k0 < K; k0 += 16) {
        float a[4], w[4];
        const int kb = k0 + c4 * 4;
        if (kb + 3 < K) {
            const float4 av = *(const float4*)(A + (size_t)(m0 + lr) * lda + kb);
            a[0] = av.x; a[1] = av.y; a[2] = av.z; a[3] = av.w;
            const float4 wv = *(const float4*)(W + (size_t)(n0 + lr) * ldw + kb);
            w[0] = wv.x; w[1] = wv.y; w[2] = wv.z; w[3] = wv.w;
        } else {
#pragma unroll
            for (int k = 0; k < 4; ++k) {
                a[k] = (kb + k < K) ? A[(size_t)(m0 + lr) * lda + kb + k] : 0.0f;
                w[k] = (kb + k < K) ? W[(size_t)(n0 + lr) * ldw + kb + k] : 0.0f;
            }
        }
        __syncthreads();
#pragma unroll
        for (int k = 0; k < 4; ++k) {
            AsT[c4 * 4 + k][lr] = a[k];
            WsT[c4 * 4 + k][lr] = w[k];
        }
        __syncthreads();
#pragma unroll
        for (int kk = 0; kk < 16; ++kk) {
            const float4 av = *(const float4*)&AsT[kk][ty * 4];
            const float4 wv = *(const float4*)&WsT[kk][tx * 4];
            acc[0][0] += av.x * wv.x; acc[0][1] += av.x * wv.y; acc[0][2] += av.x * wv.z; acc[0][3] += av.x * wv.w;
            acc[1][0] += av.y * wv.x; acc[1][1] += av.y * wv.y; acc[1][2] += av.y * wv.z; acc[1][3] += av.y * wv.w;
            acc[2][0] += av.z * wv.x; acc[2][1] += av.z * wv.y; acc[2][2] += av.z * wv.z; acc[2][3] += av.z * wv.w;
            acc[3][0] += av.w * wv.x; acc[3][1] += av.w * wv.y; acc[3][2] += av.w * wv.z; acc[3][3] += av.w * wv.w;
        }
    }

#pragma unroll
    for (int i = 0; i < 4; ++i) {
        const int m = m0 + ty * 4 + i;
#pragma unroll
        for (int j = 0; j < 4; ++j) {
            const int n = n0 + tx * 4 + j;
            float v = acc[i][j];
            if (b1) v += b1[n];
            if (b2) v += b2[n];
            const size_t idx = (size_t)m * ldc + n;
            if (accum) v += C[idx];
            C[idx] = v;
        }
    }
}

// ---------------- fused LSTM step ----------------
__global__ __launch_bounds__(256)
void lstm_step(const float* __restrict__ h_in,
               const float* __restrict__ c_in,
               float* __restrict__ c_out,
               float* __restrict__ h_out,
               const float* __restrict__ Whh, int ldw,
               const float* __restrict__ xg1, int s1,
               const float* __restrict__ xg2, int s2,
               const float* __restrict__ bih, const float* __restrict__ bhh,
               const float* __restrict__ xs, const float* __restrict__ Wxs)
{
    __shared__ float HsT[16][68];
    __shared__ float WsT[16][68];
    const int t  = threadIdx.x;
    const int ul = t & 15;
    const int bg = t >> 4;
    const int b0 = blockIdx.x * 64;
    const int u0 = blockIdx.y * 16;
    const int lr = t >> 2;
    const int c4 = t & 3;

    const int w_ul = lr >> 2, w_g = lr & 3;
    const int wrow = w_g * HID + u0 + w_ul;

    float acc[4][4];
#pragma unroll
    for (int g = 0; g < 4; ++g)
#pragma unroll
        for (int i = 0; i < 4; ++i) acc[g][i] = 0.0f;

    for (int k0 = 0; k0 < HID; k0 += 16) {
        const float4 hv = *(const float4*)(h_in + (size_t)(b0 + lr) * HID + k0 + c4 * 4);
        const float4 wv = *(const float4*)(Whh + (size_t)wrow * ldw + k0 + c4 * 4);
        __syncthreads();
        HsT[c4 * 4 + 0][lr] = hv.x; HsT[c4 * 4 + 1][lr] = hv.y;
        HsT[c4 * 4 + 2][lr] = hv.z; HsT[c4 * 4 + 3][lr] = hv.w;
        WsT[c4 * 4 + 0][lr] = wv.x; WsT[c4 * 4 + 1][lr] = wv.y;
        WsT[c4 * 4 + 2][lr] = wv.z; WsT[c4 * 4 + 3][lr] = wv.w;
        __syncthreads();
#pragma unroll
        for (int kk = 0; kk < 16; ++kk) {
            const float4 h4 = *(const float4*)&HsT[kk][bg * 4];
            const float4 w4 = *(const float4*)&WsT[kk][ul * 4];
            acc[0][0] += w4.x * h4.x; acc[0][1] += w4.x * h4.y; acc[0][2] += w4.x * h4.z; acc[0][3] += w4.x * h4.w;
            acc[1][0] += w4.y * h4.x; acc[1][1] += w4.y * h4.y; acc[1][2] += w4.y * h4.z; acc[1][3] += w4.y * h4.w;
            acc[2][0] += w4.z * h4.x; acc[2][1] += w4.z * h4.y; acc[2][2] += w4.z * h4.z; acc[2][3] += w4.z * h4.w;
            acc[3][0] += w4.w * h4.x; acc[3][1] += w4.w * h4.y; acc[3][2] += w4.w * h4.z; acc[3][3] += w4.w * h4.w;
        }
    }

    const int u = u0 + ul;
#pragma unroll
    for (int i = 0; i < 4; ++i) {
        const int b = b0 + bg * 4 + i;
        float g[4];
#pragma unroll
        for (int gg = 0; gg < 4; ++gg) {
            float v = acc[gg][i];
            const int j = gg * HID + u;
            if (xg1) v += xg1[(size_t)b * s1 + j];
            if (xg2) v += xg2[(size_t)b * s2 + j];
            if (bih) v += bih[j];
            if (bhh) v += bhh[j];
            if (xs)  v += xs[b * 3 + 0] * Wxs[j * 3 + 0]
                        + xs[b * 3 + 1] * Wxs[j * 3 + 1]
                        + xs[b * 3 + 2] * Wxs[j * 3 + 2];
            g[gg] = v;
        }
        const float cprev = c_in[(size_t)b * HID + u];
        const float cnew  = sigmf(g[1]) * cprev + sigmf(g[0]) * tanhf(g[2]);
        const float hnew  = sigmf(g[3]) * tanhf(cnew);
        c_out[(size_t)b * HID + u] = cnew;
        h_out[(size_t)b * HID + u] = hnew;
    }
}

__global__ __launch_bounds__(64)
void decoder_tail(const float* __restrict__ fuse2,
                  const float* __restrict__ outW, const float* __restrict__ outb,
                  float* __restrict__ pred, float* __restrict__ out, int tstep)
{
    const int b = blockIdx.x;
    const int t = threadIdx.x;
    float a0 = 0.f, a1 = 0.f, a2 = 0.f;
#pragma unroll
    for (int k = 0; k < 4; ++k) {
        const int u = t + k * 64;
        const float f = fuse2[b * HID + u];
        a0 += f * outW[u];
        a1 += f * outW[HID + u];
        a2 += f * outW[2 * HID + u];
    }
    for (int s = 32; s > 0; s >>= 1) {
        a0 += __shfl_down(a0, s);
        a1 += __shfl_down(a1, s);
        a2 += __shfl_down(a2, s);
    }
    if (t == 0) {
        const float p0 = pred[b * 3 + 0] + a0 + outb[0];
        const float p1 = pred[b * 3 + 1] + a1 + outb[1];
        const float p2 = pred[b * 3 + 2] + a2 + outb[2];
        pred[b * 3 + 0] = p0; pred[b * 3 + 1] = p1; pred[b * 3 + 2] = p2;
        float* o = out + ((size_t)b * HWIN + tstep) * 3;
        o[0] = p0; o[1] = p1; o[2] = p2;
    }
}

extern "C" void kernel_launch(void* const* d_in, const int* in_sizes, int n_in,
                              void* d_out, int out_size, void* d_ws, size_t ws_size,
                              hipStream_t stream)
{
    (void)in_sizes; (void)n_in; (void)out_size; (void)ws_size;
    const float* enc_pos = (const float*)d_in[0];
    const float* enc_sal = (const float*)d_in[1];
    const float* dec_pos = (const float*)d_in[2];
    const float* dec_sal = (const float*)d_in[3];
    const float *pe_Wih = (const float*)d_in[4],  *pe_Whh = (const float*)d_in[5],
                *pe_bih = (const float*)d_in[6],  *pe_bhh = (const float*)d_in[7];
    const float *se_Wih = (const float*)d_in[8],  *se_Whh = (const float*)d_in[9],
                *se_bih = (const float*)d_in[10], *se_bhh = (const float*)d_in[11];
    const float *fe_Wih = (const float*)d_in[12], *fe_Whh = (const float*)d_in[13],
                *fe_bih = (const float*)d_in[14], *fe_bhh = (const float*)d_in[15];
    const float *pd_Wih = (const float*)d_in[16], *pd_Whh = (const float*)d_in[17],
                *pd_bih = (const float*)d_in[18], *pd_bhh = (const float*)d_in[19];
    const float *sd_Wih = (const float*)d_in[20], *sd_Whh = (const float*)d_in[21],
                *sd_bih = (const float*)d_in[22], *sd_bhh = (const float*)d_in[23];
    const float *fd_Wih = (const float*)d_in[24], *fd_Whh = (const float*)d_in[25],
                *fd_bih = (const float*)d_in[26], *fd_bhh = (const float*)d_in[27];
    const float *f2_W = (const float*)d_in[28], *f2_b = (const float*)d_in[29];
    const float *out_W = (const float*)d_in[30], *out_b = (const float*)d_in[31];
    float* out = (float*)d_out;
    float* ws  = (float*)d_ws;

    // ---- workspace layout (floats) ----
    size_t off = 0;
    float* XG_ENC = ws + off; off += (size_t)8192 * 1024;
    float* BIG    = ws + off; off += (size_t)12800 * 1024;
    float* PE_SEQ = ws + off; off += (size_t)(MENC + 1) * BH;
    float* SE_SEQ = ws + off; off += (size_t)(MENC + 1) * BH;
    float* FE_SEQ = ws + off; off += (size_t)(MENC + 1) * BH;
    float* SD_SEQ = ws + off; off += (size_t)(HWIN + 1) * BH;
    float* PE_C  = ws + off; off += BH;
    float* SE_C  = ws + off; off += BH;
    float* FE_C  = ws + off; off += BH;
    float* FD_C  = ws + off; off += BH;
    float* GBIAS = ws + off; off += (size_t)BATCH * 1024;
    float* PDH0  = ws + off; off += BH;
    float* PDH1  = ws + off; off += BH;
    float* HFD   = ws + off; off += BH;
    float* FUSE2 = ws + off; off += BH;
    float* PRED  = ws + off; off += (size_t)BATCH * 4;
    // bf16 buffers (ushort), reused across phases
    ushort* ABUF = (ushort*)(ws + off); off += (size_t)52428800 / 2;  // 12800x4096 bf16 max
    ushort* WBUF = (ushort*)(ws + off); off += (size_t)(1024 * 4096) / 2;
    ushort* WFE  = (ushort*)(ws + off); off += (size_t)(1024 * 512) / 2;
    ushort* WFD  = (ushort*)(ws + off); off += (size_t)(1024 * 512) / 2;

    hipMemsetAsync(PE_SEQ, 0, (size_t)BH * 4, stream);
    hipMemsetAsync(SE_SEQ, 0, (size_t)BH * 4, stream);
    hipMemsetAsync(FE_SEQ, 0, (size_t)BH * 4, stream);
    hipMemsetAsync(PE_C, 0, (size_t)BH * 4, stream);
    hipMemsetAsync(SE_C, 0, (size_t)BH * 4, stream);
    hipMemsetAsync(FE_C, 0, (size_t)BH * 4, stream);
    hipMemcpyAsync(PRED, dec_pos, (size_t)BATCH * 3 * 4, hipMemcpyDeviceToDevice, stream);

    auto gemm = [&](const float* A, const float* W, const float* b1, const float* b2,
                    float* C, int M, int N, int K, int lda, int ldw, int ldc, int accum) {
        gemm_tn<<<dim3(N / 64, M / 64), 256, 0, stream>>>(A, W, b1, b2, C, M, N, K, lda, ldw, ldc, accum);
    };
    auto mgemm = [&](const ushort* A, const ushort* W, float* C,
                     int M, int N, int K, int lda, int ldw, int ldc) {
        gemm_mfma_bt<<<dim3(N / 128, M / 128), 256, 0, stream>>>(A, W, C, M, N, K, lda, ldw, ldc);
    };
    auto cvt = [&](const float* in, ushort* outp, size_t n) {
        const int n4 = (int)(n / 4);
        cvt_f32_bf16<<<(n4 + 255) / 256, 256, 0, stream>>>(in, outp, n4);
    };
    auto step = [&](const float* h_in, const float* c_in, float* c_out, float* h_out,
                    const float* Whh, int ldw, const float* xg1, int s1,
                    const float* xg2, int s2, const float* bih, const float* bhh,
                    const float* xs, const float* Wxs) {
        lstm_step<<<dim3(BATCH / 64, HID / 16), 256, 0, stream>>>(
            h_in, c_in, c_out, h_out, Whh, ldw, xg1, s1, xg2, s2, bih, bhh, xs, Wxs);
    };

    // ---- encoder: pe LSTM (din=3, stays fp32) ----
    gemm(enc_pos, pe_Wih, nullptr, nullptr, XG_ENC, BATCH * MENC, 1024, 3, 3, 3, 1024, 0);
    for (int t = 0; t < MENC; ++t)
        step(PE_SEQ + (size_t)t * BH, PE_C, PE_C, PE_SEQ + (size_t)(t + 1) * BH,
             pe_Whh, HID, XG_ENC + (size_t)t * 1024, MENC * 1024, nullptr, 0,
             pe_bih, pe_bhh, nullptr, nullptr);

    // ---- encoder: se LSTM — bf16 MFMA projection ----
    cvt(enc_sal, ABUF, (size_t)BATCH * MENC * SALSZ);
    cvt(se_Wih, WBUF, (size_t)1024 * SALSZ);
    mgemm(ABUF, WBUF, XG_ENC, BATCH * MENC, 1024, SALSZ, SALSZ, SALSZ, 1024);
    for (int t = 0; t < MENC; ++t)
        step(SE_SEQ + (size_t)t * BH, SE_C, SE_C, SE_SEQ + (size_t)(t + 1) * BH,
             se_Whh, HID, XG_ENC + (size_t)t * 1024, MENC * 1024, nullptr, 0,
             se_bih, se_bhh, nullptr, nullptr);

    // ---- encoder: fe LSTM — concat (bf16) + single MFMA GEMM K=512 ----
    build_conc_bf16<<<(BATCH * MENC * 512) / 1024, 256, 0, stream>>>(SE_SEQ, PE_SEQ, ABUF);
    cvt(fe_Wih, WFE, (size_t)1024 * 512);
    mgemm(ABUF, WFE, XG_ENC, BATCH * MENC, 1024, 512, 512, 512, 1024);
    for (int t = 0; t < MENC; ++t)
        step(FE_SEQ + (size_t)t * BH, FE_C, FE_C, FE_SEQ + (size_t)(t + 1) * BH,
             fe_Whh, HID, XG_ENC + (size_t)t * BATCH * 1024, 1024, nullptr, 0,
             fe_bih, fe_bhh, nullptr, nullptr);

    // ---- decoder sd chain — bf16 MFMA projection ----
    cvt(dec_sal, ABUF, (size_t)BATCH * HWIN * SALSZ);
    cvt(sd_Wih, WBUF, (size_t)1024 * SALSZ);
    mgemm(ABUF, WBUF, BIG, BATCH * HWIN, 1024, SALSZ, SALSZ, SALSZ, 1024);
    for (int t = 0; t < HWIN; ++t)
        step(t == 0 ? SE_SEQ + (size_t)MENC * BH : SD_SEQ + (size_t)t * BH,
             SE_C, SE_C, SD_SEQ + (size_t)(t + 1) * BH,
             sd_Whh, HID, BIG + (size_t)t * 1024, HWIN * 1024, nullptr, 0,
             sd_bih, sd_bhh, nullptr, nullptr);

    // ---- fd precomputations ----
    // SD h-states flatten to rows (t,b) directly: plain convert of SD_SEQ+BH
    cvt(SD_SEQ + BH, ABUF, (size_t)BATCH * HWIN * HID);
    cvt(fd_Wih, WFD, (size_t)1024 * 512);
    mgemm(ABUF, WFD, BIG, BATCH * HWIN, 1024, HID, HID, 512, 1024);  // h2-half (cols 0:256)
    gemm(FE_SEQ + (size_t)MENC * BH, fd_Whh, fd_bih, fd_bhh, GBIAS, BATCH, 1024, HID, HID, HID, 1024, 0);

    // ---- serial decoder loop ----
    float* pdh[2] = { PDH0, PDH1 };
    for (int t = 0; t < HWIN; ++t) {
        const float* h1in = (t == 0) ? (PE_SEQ + (size_t)MENC * BH) : pdh[t & 1];
        float* h1out = pdh[(t + 1) & 1];
        step(h1in, PE_C, PE_C, h1out, pd_Whh, HID, nullptr, 0, nullptr, 0,
             pd_bih, pd_bhh, PRED, pd_Wih);
        step(h1out, FE_C, FD_C, HFD, fd_Wih + HID, 2 * HID,
             BIG + (size_t)t * BATCH * 1024, 1024, GBIAS, 1024,
             nullptr, nullptr, nullptr, nullptr);
        gemm(HFD, f2_W, f2_b, nullptr, FUSE2, BATCH, HID, HID, HID, HID, HID, 0);
        decoder_tail<<<BATCH, 64, 0, stream>>>(FUSE2, out_W, out_b, PRED, out, t);
    }
}

// Round 3
// 1800.682 us; speedup vs baseline: 3.2375x; 2.0282x over previous
//
#include <hip/hip_runtime.h>

#define HID 256
#define BATCH 512
#define MENC 16
#define HWIN 25
#define SALSZ 4096
#define BH (BATCH * HID)   // 131072

typedef __attribute__((ext_vector_type(8))) short bf16x8;
typedef __attribute__((ext_vector_type(4))) float f32x4;

__device__ __forceinline__ float sigmf(float x) { return 1.0f / (1.0f + __expf(-x)); }
__device__ __forceinline__ ushort f2bf(float f) {
    uint32_t u = __float_as_uint(f);
    return (ushort)((u + 0x7fffu + ((u >> 16) & 1u)) >> 16);   // RNE
}

#define GLOAD_LDS(gp, lp) \
    __builtin_amdgcn_global_load_lds((const __attribute__((address_space(1))) void*)(gp), \
                                     (__attribute__((address_space(3))) void*)(lp), 16, 0, 0)

// ---------------- fp32 -> bf16 ----------------
__global__ __launch_bounds__(256)
void cvt_f32_bf16(const float* __restrict__ in, ushort* __restrict__ out, int n4)
{
    const int i = blockIdx.x * 256 + threadIdx.x;
    if (i >= n4) return;
    const float4 v = *(const float4*)(in + (size_t)i * 4);
    *(ushort4*)(out + (size_t)i * 4) = make_ushort4(f2bf(v.x), f2bf(v.y), f2bf(v.z), f2bf(v.w));
}

// ---------------- big bf16 MFMA GEMM: C[M,N] = A[M,K] @ W[N,K]^T ----------------
// m97 structure + XCD-aware bijective block swizzle (T1).
__global__ __launch_bounds__(256)
void gemm_mfma_bt(const ushort* __restrict__ A, const ushort* __restrict__ W,
                  float* __restrict__ C, int M, int N, int K,
                  int lda, int ldw, int ldc)
{
    __shared__ ushort As[128 * 32];
    __shared__ ushort Bs[128 * 32];
    const int t    = threadIdx.x;
    const int lane = t & 63, wid = t >> 6;

    const int gx = gridDim.x, nwg = gx * gridDim.y;
    int bid = blockIdx.y * gx + blockIdx.x;
    if ((nwg & 7) == 0) bid = (bid & 7) * (nwg >> 3) + (bid >> 3);
    const int bx = bid % gx, by = bid / gx;

    const int m0 = by * 128, n0 = bx * 128;
    const int wr = wid >> 1, wc = wid & 1;

    f32x4 acc[4][4] = {};

    const int sr = wid * 16 + (lane >> 2);
    const int sk = (lane & 3) * 8;
    const ushort* Ag = A + (size_t)(m0 + sr) * lda + sk;
    const ushort* Wg = W + (size_t)(n0 + sr) * ldw + sk;
    ushort* Al = As + wid * 512;
    ushort* Bl = Bs + wid * 512;

    const int fr = lane & 15;
    const int fk = (lane >> 4) * 8;

    for (int k0 = 0; k0 < K; k0 += 32) {
        GLOAD_LDS(Ag,                    Al);
        GLOAD_LDS(Ag + (size_t)64 * lda, Al + 2048);
        GLOAD_LDS(Wg,                    Bl);
        GLOAD_LDS(Wg + (size_t)64 * ldw, Bl + 2048);
        Ag += 32; Wg += 32;
        __syncthreads();

        bf16x8 af[4], bfr[4];
#pragma unroll
        for (int m = 0; m < 4; ++m)
            af[m] = *(const bf16x8*)(As + (wr * 64 + m * 16 + fr) * 32 + fk);
#pragma unroll
        for (int n = 0; n < 4; ++n)
            bfr[n] = *(const bf16x8*)(Bs + (wc * 64 + n * 16 + fr) * 32 + fk);
#pragma unroll
        for (int m = 0; m < 4; ++m)
#pragma unroll
            for (int n = 0; n < 4; ++n)
                acc[m][n] = __builtin_amdgcn_mfma_f32_16x16x32_bf16(af[m], bfr[n], acc[m][n], 0, 0, 0);
        __syncthreads();
    }

    const int cl = lane & 15, ch = lane >> 4;
#pragma unroll
    for (int m = 0; m < 4; ++m)
#pragma unroll
        for (int n = 0; n < 4; ++n)
#pragma unroll
            for (int r = 0; r < 4; ++r)
                C[(size_t)(m0 + wr * 64 + m * 16 + ch * 4 + r) * ldc
                  + n0 + wc * 64 + n * 16 + cl] = acc[m][n][r];
}

// ---------------- fp32 tiled GEMM (tiny-K / one-off) ----------------
__global__ __launch_bounds__(256)
void gemm_tn(const float* __restrict__ A, const float* __restrict__ W,
             const float* __restrict__ b1, const float* __restrict__ b2,
             float* __restrict__ C,
             int M, int N, int K, int lda, int ldw, int ldc)
{
    __shared__ float AsT[16][68];
    __shared__ float WsT[16][68];
    const int t  = threadIdx.x;
    const int tx = t & 15, ty = t >> 4;
    const int m0 = blockIdx.y * 64, n0 = blockIdx.x * 64;
    const int lr = t >> 2;
    const int c4 = t & 3;

    float acc[4][4];
#pragma unroll
    for (int i = 0; i < 4; ++i)
#pragma unroll
        for (int j = 0; j < 4; ++j) acc[i][j] = 0.0f;

    for (int k0 = 0; k0 < K; k0 += 16) {
        float a[4], w[4];
        const int kb = k0 + c4 * 4;
        if (kb + 3 < K) {
            const float4 av = *(const float4*)(A + (size_t)(m0 + lr) * lda + kb);
            a[0] = av.x; a[1] = av.y; a[2] = av.z; a[3] = av.w;
            const float4 wv = *(const float4*)(W + (size_t)(n0 + lr) * ldw + kb);
            w[0] = wv.x; w[1] = wv.y; w[2] = wv.z; w[3] = wv.w;
        } else {
#pragma unroll
            for (int k = 0; k < 4; ++k) {
                a[k] = (kb + k < K) ? A[(size_t)(m0 + lr) * lda + kb + k] : 0.0f;
                w[k] = (kb + k < K) ? W[(size_t)(n0 + lr) * ldw + kb + k] : 0.0f;
            }
        }
        __syncthreads();
#pragma unroll
        for (int k = 0; k < 4; ++k) {
            AsT[c4 * 4 + k][lr] = a[k];
            WsT[c4 * 4 + k][lr] = w[k];
        }
        __syncthreads();
#pragma unroll
        for (int kk = 0; kk < 16; ++kk) {
            const float4 av = *(const float4*)&AsT[kk][ty * 4];
            const float4 wv = *(const float4*)&WsT[kk][tx * 4];
            acc[0][0] += av.x * wv.x; acc[0][1] += av.x * wv.y; acc[0][2] += av.x * wv.z; acc[0][3] += av.x * wv.w;
            acc[1][0] += av.y * wv.x; acc[1][1] += av.y * wv.y; acc[1][2] += av.y * wv.z; acc[1][3] += av.y * wv.w;
            acc[2][0] += av.z * wv.x; acc[2][1] += av.z * wv.y; acc[2][2] += av.z * wv.z; acc[2][3] += av.z * wv.w;
            acc[3][0] += av.w * wv.x; acc[3][1] += av.w * wv.y; acc[3][2] += av.w * wv.z; acc[3][3] += av.w * wv.w;
        }
    }

#pragma unroll
    for (int i = 0; i < 4; ++i) {
        const int m = m0 + ty * 4 + i;
#pragma unroll
        for (int j = 0; j < 4; ++j) {
            const int n = n0 + tx * 4 + j;
            float v = acc[i][j];
            if (b1) v += b1[n];
            if (b2) v += b2[n];
            C[(size_t)m * ldc + n] = v;
        }
    }
}

// ---------------- MFMA LSTM step ----------------
// Block = 64 b x 16 u (x4 gates). Full 64x256 H and W tiles staged to LDS via
// global_load_lds with XOR-swizzled 16B units (source-side swizzle + swizzled
// ds_read, LDS dest linear — rule #21), one barrier, 32 MFMA/wave, fused epilogue.
struct StepArgs {
    const ushort* hb_in;  int ldh_in;
    const float*  c_in;
    float*        c_out;
    const ushort* Whh;    int ldwh;   // bf16 [1024][ldwh]
    const float*  xg1;  int s1;
    const float*  xg2;  int s2;
    const float*  bias1;
    const float*  bias2;
    const float*  xs;                 // [512][3] fp32
    const float*  Wxs;                // [1024][3] fp32
    ushort*       hb_out; int ldh_out;
    float*        h_out;
};

__global__ __launch_bounds__(256)
void lstm_step_mfma(StepArgs P0, StepArgs P1)
{
    const StepArgs P = (blockIdx.z == 0) ? P0 : P1;
    __shared__ ushort Hs[64 * 256];   // 32 KB
    __shared__ ushort Ws[64 * 256];   // 32 KB
    const int t = threadIdx.x, lane = t & 63, w = t >> 6;
    const int b0 = blockIdx.x * 64;
    const int u0 = blockIdx.y * 16;

    {
        const int sub = lane >> 5;
        const int uu  = lane & 31;
#pragma unroll
        for (int i = 0; i < 8; ++i) {
            const int row = i * 8 + w * 2 + sub;
            const int su  = uu ^ (row & 7);
            GLOAD_LDS(P.hb_in + (size_t)(b0 + row) * P.ldh_in + su * 8,
                      Hs + i * 2048 + w * 512);
            const int wr = (row >> 4) * HID + u0 + (row & 15);   // vn = g*16+u_l -> W row
            GLOAD_LDS(P.Whh + (size_t)wr * P.ldwh + su * 8,
                      Ws + i * 2048 + w * 512);
        }
    }
    __syncthreads();

    f32x4 acc[4] = {};
    const int fr = lane & 15, fq = lane >> 4;
#pragma unroll
    for (int ks = 0; ks < 8; ++ks) {
        const int ku = ks * 4 + fq;
        const int ar = w * 16 + fr;
        const bf16x8 af = *(const bf16x8*)(Hs + ar * 256 + (ku ^ (ar & 7)) * 8);
#pragma unroll
        for (int g = 0; g < 4; ++g) {
            const int vr = g * 16 + fr;
            const bf16x8 bf = *(const bf16x8*)(Ws + vr * 256 + (ku ^ (vr & 7)) * 8);
            acc[g] = __builtin_amdgcn_mfma_f32_16x16x32_bf16(af, bf, acc[g], 0, 0, 0);
        }
    }

    const int u = u0 + fr;
#pragma unroll
    for (int r = 0; r < 4; ++r) {
        const int b = b0 + w * 16 + fq * 4 + r;
        float gv[4];
#pragma unroll
        for (int g = 0; g < 4; ++g) {
            float v = acc[g][r];
            const int j = g * HID + u;
            if (P.xg1)   v += P.xg1[(size_t)b * P.s1 + j];
            if (P.xg2)   v += P.xg2[(size_t)b * P.s2 + j];
            if (P.bias1) v += P.bias1[j];
            if (P.bias2) v += P.bias2[j];
            if (P.xs)    v += P.xs[b * 3 + 0] * P.Wxs[j * 3 + 0]
                            + P.xs[b * 3 + 1] * P.Wxs[j * 3 + 1]
                            + P.xs[b * 3 + 2] * P.Wxs[j * 3 + 2];
            gv[g] = v;
        }
        const float cp = P.c_in[(size_t)b * HID + u];
        const float cn = sigmf(gv[1]) * cp + sigmf(gv[0]) * tanhf(gv[2]);
        const float hn = sigmf(gv[3]) * tanhf(cn);
        P.c_out[(size_t)b * HID + u] = cn;
        if (P.hb_out) P.hb_out[(size_t)b * P.ldh_out + u] = f2bf(hn);
        if (P.h_out)  P.h_out[(size_t)b * HID + u] = hn;
    }
}

// ---------------- G = out_W @ f2_W, c3 = out_b + out_W @ f2_b ----------------
__global__ __launch_bounds__(256)
void precompute_G(const float* __restrict__ f2W, const float* __restrict__ f2b,
                  const float* __restrict__ outW, const float* __restrict__ outb,
                  float* __restrict__ G, float* __restrict__ c3)
{
    const int k = threadIdx.x;
    float g0 = 0.f, g1 = 0.f, g2 = 0.f;
    for (int n = 0; n < HID; ++n) {
        const float w = f2W[n * HID + k];
        g0 += outW[n] * w;
        g1 += outW[HID + n] * w;
        g2 += outW[2 * HID + n] * w;
    }
    G[k] = g0; G[HID + k] = g1; G[2 * HID + k] = g2;
    if (k < 3) {
        float s = outb[k];
        for (int n = 0; n < HID; ++n) s += outW[k * HID + n] * f2b[n];
        c3[k] = s;
    }
}

// ---------------- delta = hfd @ G^T + c3 ; pred += delta ; out write ----------------
__global__ __launch_bounds__(64)
void decoder_tail(const float* __restrict__ hfd, const float* __restrict__ G,
                  const float* __restrict__ c3,
                  float* __restrict__ pred, float* __restrict__ out, int tstep)
{
    const int b = blockIdx.x;
    const int t = threadIdx.x;
    float a0 = 0.f, a1 = 0.f, a2 = 0.f;
#pragma unroll
    for (int k = 0; k < 4; ++k) {
        const int u = t + k * 64;
        const float f = hfd[b * HID + u];
        a0 += f * G[u];
        a1 += f * G[HID + u];
        a2 += f * G[2 * HID + u];
    }
    for (int s = 32; s > 0; s >>= 1) {
        a0 += __shfl_down(a0, s);
        a1 += __shfl_down(a1, s);
        a2 += __shfl_down(a2, s);
    }
    if (t == 0) {
        const float p0 = pred[b * 3 + 0] + a0 + c3[0];
        const float p1 = pred[b * 3 + 1] + a1 + c3[1];
        const float p2 = pred[b * 3 + 2] + a2 + c3[2];
        pred[b * 3 + 0] = p0; pred[b * 3 + 1] = p1; pred[b * 3 + 2] = p2;
        float* o = out + ((size_t)b * HWIN + tstep) * 3;
        o[0] = p0; o[1] = p1; o[2] = p2;
    }
}

extern "C" void kernel_launch(void* const* d_in, const int* in_sizes, int n_in,
                              void* d_out, int out_size, void* d_ws, size_t ws_size,
                              hipStream_t stream)
{
    (void)in_sizes; (void)n_in; (void)out_size; (void)ws_size;
    const float* enc_pos = (const float*)d_in[0];
    const float* enc_sal = (const float*)d_in[1];
    const float* dec_pos = (const float*)d_in[2];
    const float* dec_sal = (const float*)d_in[3];
    const float *pe_Wih = (const float*)d_in[4],  *pe_Whh = (const float*)d_in[5],
                *pe_bih = (const float*)d_in[6],  *pe_bhh = (const float*)d_in[7];
    const float *se_Wih = (const float*)d_in[8],  *se_Whh = (const float*)d_in[9],
                *se_bih = (const float*)d_in[10], *se_bhh = (const float*)d_in[11];
    const float *fe_Wih = (const float*)d_in[12], *fe_Whh = (const float*)d_in[13],
                *fe_bih = (const float*)d_in[14], *fe_bhh = (const float*)d_in[15];
    const float *pd_Wih = (const float*)d_in[16], *pd_Whh = (const float*)d_in[17],
                *pd_bih = (const float*)d_in[18], *pd_bhh = (const float*)d_in[19];
    const float *sd_Wih = (const float*)d_in[20], *sd_Whh = (const float*)d_in[21],
                *sd_bih = (const float*)d_in[22], *sd_bhh = (const float*)d_in[23];
    const float *fd_Wih = (const float*)d_in[24], *fd_Whh = (const float*)d_in[25],
                *fd_bih = (const float*)d_in[26], *fd_bhh = (const float*)d_in[27];
    const float *f2_W = (const float*)d_in[28], *f2_b = (const float*)d_in[29];
    const float *out_W = (const float*)d_in[30], *out_b = (const float*)d_in[31];
    float* out = (float*)d_out;
    float* ws  = (float*)d_ws;

    size_t off = 0;
    float* XG_SE = ws + off; off += (size_t)8192 * 1024;   // se x-proj (b,t); then fe x-proj (t,b)
    float* XG_PE = ws + off; off += (size_t)8192 * 1024;   // pe x-proj (b,t)
    float* BIG   = ws + off; off += (size_t)12800 * 1024;  // sd x-proj (b,t); then fd Xh2 (t,b)
    float* GBIAS = ws + off; off += (size_t)BATCH * 1024;
    float* PE_C  = ws + off; off += BH;
    float* SE_C  = ws + off; off += BH;
    float* FE_C  = ws + off; off += BH;
    float* FD_C  = ws + off; off += BH;
    float* FEH   = ws + off; off += BH;
    float* HFD   = ws + off; off += BH;
    float* PRED  = ws + off; off += 2048;
    float* Gm    = ws + off; off += 1024;
    float* C3    = ws + off; off += 8;
    ushort* ABUF = (ushort*)(ws + off); off += ((size_t)12800 * 4096) / 2;
    ushort* WSE  = (ushort*)(ws + off); off += ((size_t)1024 * 4096) / 2;
    ushort* WSD  = (ushort*)(ws + off); off += ((size_t)1024 * 4096) / 2;
    ushort* WFE  = (ushort*)(ws + off); off += ((size_t)1024 * 512) / 2;
    ushort* WFD  = (ushort*)(ws + off); off += ((size_t)1024 * 512) / 2;
    ushort* WHpe = (ushort*)(ws + off); off += ((size_t)1024 * 256) / 2;
    ushort* WHse = (ushort*)(ws + off); off += ((size_t)1024 * 256) / 2;
    ushort* WHfe = (ushort*)(ws + off); off += ((size_t)1024 * 256) / 2;
    ushort* WHsd = (ushort*)(ws + off); off += ((size_t)1024 * 256) / 2;
    ushort* WHpd = (ushort*)(ws + off); off += ((size_t)1024 * 256) / 2;
    ushort* CONC = (ushort*)(ws + off); off += ((size_t)MENC * 512 * 512) / 2;  // [t*512+b][512]
    ushort* SDB  = (ushort*)(ws + off); off += ((size_t)HWIN * BH) / 2;         // [t*512+b][256]
    ushort* H1B0 = (ushort*)(ws + off); off += BH / 2;
    ushort* H1B1 = (ushort*)(ws + off); off += BH / 2;
    ushort* FEB0 = (ushort*)(ws + off); off += BH / 2;
    ushort* FEB1 = (ushort*)(ws + off); off += BH / 2;
    ushort* ZB   = (ushort*)(ws + off); off += BH / 2;

    hipMemsetAsync(ZB, 0, (size_t)BH * 2, stream);
    hipMemsetAsync(PE_C, 0, (size_t)BH * 4, stream);
    hipMemsetAsync(SE_C, 0, (size_t)BH * 4, stream);
    hipMemsetAsync(FE_C, 0, (size_t)BH * 4, stream);
    hipMemcpyAsync(PRED, dec_pos, (size_t)BATCH * 3 * 4, hipMemcpyDeviceToDevice, stream);

    auto cvt = [&](const float* in, ushort* outp, size_t n) {
        const int n4 = (int)(n / 4);
        cvt_f32_bf16<<<(n4 + 255) / 256, 256, 0, stream>>>(in, outp, n4);
    };
    auto mgemm = [&](const ushort* A, const ushort* W, float* C,
                     int M, int N, int K, int lda, int ldw, int ldc) {
        gemm_mfma_bt<<<dim3(N / 128, M / 128), 256, 0, stream>>>(A, W, C, M, N, K, lda, ldw, ldc);
    };
    auto mkstep = [&](const ushort* hb_in, int ldh_in, const float* c_in, float* c_out,
                      const ushort* Whh, int ldwh, const float* xg1, int s1,
                      const float* xg2, int s2, const float* b1, const float* b2,
                      const float* xs, const float* Wxs,
                      ushort* hb_out, int ldh_out, float* h_out) {
        StepArgs a;
        a.hb_in = hb_in; a.ldh_in = ldh_in; a.c_in = c_in; a.c_out = c_out;
        a.Whh = Whh; a.ldwh = ldwh;
        a.xg1 = xg1; a.s1 = s1; a.xg2 = xg2; a.s2 = s2; a.bias1 = b1; a.bias2 = b2;
        a.xs = xs; a.Wxs = Wxs; a.hb_out = hb_out; a.ldh_out = ldh_out; a.h_out = h_out;
        return a;
    };
    auto step2 = [&](const StepArgs& a, const StepArgs& b, int nz) {
        lstm_step_mfma<<<dim3(BATCH / 64, HID / 16, nz), 256, 0, stream>>>(a, b);
    };

    // ---- one-time conversions / precomputes ----
    cvt(se_Wih, WSE, (size_t)1024 * SALSZ);
    cvt(sd_Wih, WSD, (size_t)1024 * SALSZ);
    cvt(fe_Wih, WFE, (size_t)1024 * 512);
    cvt(fd_Wih, WFD, (size_t)1024 * 512);
    cvt(pe_Whh, WHpe, (size_t)1024 * 256);
    cvt(se_Whh, WHse, (size_t)1024 * 256);
    cvt(fe_Whh, WHfe, (size_t)1024 * 256);
    cvt(sd_Whh, WHsd, (size_t)1024 * 256);
    cvt(pd_Whh, WHpd, (size_t)1024 * 256);
    cvt(enc_sal, ABUF, (size_t)8192 * SALSZ);
    precompute_G<<<1, 256, 0, stream>>>(f2_W, f2_b, out_W, out_b, Gm, C3);

    // ---- encoder x-projections ----
    gemm_tn<<<dim3(16, 128), 256, 0, stream>>>(enc_pos, pe_Wih, nullptr, nullptr, XG_PE,
                                               8192, 1024, 3, 3, 3, 1024);
    mgemm(ABUF, WSE, XG_SE, 8192, 1024, SALSZ, SALSZ, SALSZ, 1024);

    // ---- fused pe+se encoder chains ----
    for (int t = 0; t < MENC; ++t) {
        ushort* cprev = CONC + (size_t)(t - 1) * 512 * 512;   // used only for t>0
        StepArgs se_a = mkstep(t == 0 ? ZB : cprev, t == 0 ? HID : 512, SE_C, SE_C,
                               WHse, HID, XG_SE + (size_t)t * 1024, MENC * 1024, nullptr, 0,
                               se_bih, se_bhh, nullptr, nullptr,
                               CONC + (size_t)t * 512 * 512, 512, nullptr);
        StepArgs pe_a = mkstep(t == 0 ? ZB : cprev + 256, t == 0 ? HID : 512, PE_C, PE_C,
                               WHpe, HID, XG_PE + (size_t)t * 1024, MENC * 1024, nullptr, 0,
                               pe_bih, pe_bhh, nullptr, nullptr,
                               CONC + (size_t)t * 512 * 512 + 256, 512, nullptr);
        step2(se_a, pe_a, 2);
    }

    // ---- fe x-proj (rows t,b) + sd x-proj ----
    mgemm(CONC, WFE, XG_SE, 8192, 1024, 512, 512, 512, 1024);
    cvt(dec_sal, ABUF, (size_t)12800 * SALSZ);
    mgemm(ABUF, WSD, BIG, 12800, 1024, SALSZ, SALSZ, SALSZ, 1024);

    // ---- fused fe+sd chains (fe active first 16 steps) ----
    ushort* seF = CONC + (size_t)(MENC - 1) * 512 * 512;       // se final h
    for (int t = 0; t < HWIN; ++t) {
        StepArgs sd_a = mkstep(t == 0 ? seF : SDB + (size_t)(t - 1) * BH, t == 0 ? 512 : HID,
                               SE_C, SE_C, WHsd, HID,
                               BIG + (size_t)t * 1024, HWIN * 1024, nullptr, 0,
                               sd_bih, sd_bhh, nullptr, nullptr,
                               SDB + (size_t)t * BH, HID, nullptr);
        if (t < MENC) {
            StepArgs fe_a = mkstep(t == 0 ? ZB : ((t & 1) ? FEB0 : FEB1), HID, FE_C, FE_C,
                                   WHfe, HID, XG_SE + (size_t)t * 512 * 1024, 1024, nullptr, 0,
                                   fe_bih, fe_bhh, nullptr, nullptr,
                                   (t & 1) ? FEB1 : FEB0, HID, FEH);
            step2(sd_a, fe_a, 2);
        } else {
            step2(sd_a, sd_a, 1);
        }
    }

    // ---- fd precomputations ----
    mgemm(SDB, WFD, BIG, 12800, 1024, HID, HID, 512, 1024);   // Xh2 (rows t,b)
    gemm_tn<<<dim3(16, 8), 256, 0, stream>>>(FEH, fd_Whh, fd_bih, fd_bhh, GBIAS,
                                             BATCH, 1024, HID, HID, HID, 1024);

    // ---- serial decoder loop: pd -> fd -> tail ----
    ushort* peF = CONC + (size_t)(MENC - 1) * 512 * 512 + 256;  // pe final h
    for (int t = 0; t < HWIN; ++t) {
        const ushort* h1in = (t == 0) ? peF : ((t & 1) ? H1B0 : H1B1);
        ushort* h1out = (t & 1) ? H1B1 : H1B0;
        StepArgs pd_a = mkstep(h1in, (t == 0) ? 512 : HID, PE_C, PE_C, WHpd, HID,
                               nullptr, 0, nullptr, 0, pd_bih, pd_bhh,
                               PRED, pd_Wih, h1out, HID, nullptr);
        step2(pd_a, pd_a, 1);
        StepArgs fd_a = mkstep(h1out, HID, FE_C, FD_C, WFD + 256, 512,   // fd_Wih cols 256:512
                               BIG + (size_t)t * 512 * 1024, 1024, GBIAS, 1024,
                               nullptr, nullptr, nullptr, nullptr, nullptr, HID, HFD);
        step2(fd_a, fd_a, 1);
        decoder_tail<<<BATCH, 64, 0, stream>>>(HFD, Gm, C3, PRED, out, t);
    }
}